// Round 9
// baseline (122.776 us; speedup 1.0000x reference)
//
#include <hip/hip_runtime.h>
#include <hip/hip_bf16.h>
#include <stdint.h>

typedef __bf16 bf16_t;
typedef bf16_t bf16x8 __attribute__((ext_vector_type(8)));
typedef float f32x4 __attribute__((ext_vector_type(4)));

#define DEVI static __device__ __forceinline__

constexpr int NB = 32, CIN = 256, COUT = 256, KNUM = 6, ET = 3, TDIM = 64, VV = 25;
constexpr int KD   = KNUM * CIN;       // 1536 contraction dim (k,ci)
constexpr long OUT0 = (long)NB * COUT * TDIM * VV;  // 13107200 (x_sum elems)
constexpr int ACNT = ET * VV * VV;     // 1875 (A copy)

// wp3: W in fragment-order. 24 steps x 2048 chunks x 16B = 768 KB. (R7 layout)
constexpr int NSTEP = 24;              // 4 cb x 6 k
constexpr int WP3_CHUNKS = NSTEP * 2048;
constexpr size_t WP3_BYTES  = (size_t)WP3_CHUNKS * 16;      // 768 KB
constexpr size_t BIAS_OFF   = WP3_BYTES;
constexpr size_t BIAS_BYTES = (size_t)NB * VV * COUT * 4;   // bias [n][w][c] f32
constexpr size_t WS_NEED    = BIAS_OFF + BIAS_BYTES;

DEVI unsigned packbf(float lo, float hi) {
  unsigned short a = __builtin_bit_cast(unsigned short, (bf16_t)lo);
  unsigned short b = __builtin_bit_cast(unsigned short, (bf16_t)hi);
  return ((unsigned)b << 16) | (unsigned)a;
}

// ---------------- prep: wp3 fragment-layout + bias table + A copy ----------
__global__ __launch_bounds__(256) void prep_kernel(
    const float* __restrict__ A, const float* __restrict__ Bm,
    const float* __restrict__ lam_p, const float* __restrict__ W,
    const float* __restrict__ bvec, bf16_t* __restrict__ wp3,
    float* __restrict__ biasmat, float* __restrict__ outA)
{
  int idx = blockIdx.x * 256 + threadIdx.x;
  constexpr int S1 = WP3_CHUNKS;            // 49152 (one 16B chunk per thread)
  constexpr int S2 = S1 + NB * VV * COUT;   // +204800
  constexpr int S3 = S2 + ACNT;
  if (idx < S1) {
    int s  = idx >> 11;
    int r  = idx & 2047;
    int mi = r >> 7;
    int kk = (r >> 6) & 1;
    int ln = r & 63;
    int lg = ln >> 4, lw = ln & 15;
    int cb = s / 6, k = s - cb * 6;
    int cibase = cb * 64 + (lg + 4 * kk) * 8;
    int col = (k << 8) + mi * 16 + lw;
    bf16_t* dst = wp3 + ((long)idx << 3);
    #pragma unroll
    for (int e = 0; e < 8; ++e)
      dst[e] = (bf16_t)W[(cibase + e) * KD + col];
  } else if (idx < S2) {
    // bias[n][w][c] = sum_k b[k*256+c] * S[n,k,w],  S = col-sum of M (lam folded)
    int j = idx - S1;
    int c = j & 255;
    int nw = j >> 8;
    int w = nw % VV;
    int n = nw / VV;
    float lam = lam_p[0];
    float s = 0.f;
    for (int k = 0; k < KNUM; ++k) {
      float sk = 0.f;
      if (k < ET) {
        for (int v = 0; v < VV; ++v) sk += A[(k * VV + v) * VV + w];
      } else {
        for (int v = 0; v < VV; ++v) sk += Bm[(((n * ET) + (k - ET)) * VV + v) * VV + w];
        sk *= lam;
      }
      s += bvec[(k << 8) + c] * sk;
    }
    biasmat[j] = s;
  } else if (idx < S3) {
    int j = idx - S2;
    outA[j] = A[j];   // second tuple output: A passthrough
  }
}

// ---------------- fused kernel (c-split for occupancy) -----------------------
// Grid 1024: block = (half of c-range, n, 4 t's). Per step (cb,k):
// MFMA#1 Xs x Ms -> Bs[buf] (dbuf, XOR swizzle, b64 pack-writes); 1 barrier;
// MFMA#2 (af2 from wp3 global, acc 2x4). Epilogue via LDS bounce for dense
// out writes. Registers ~105-120 -> 4 waves/SIMD, 2 blocks/CU.
__global__ __launch_bounds__(512, 4) void fused_kernel(
    const float* __restrict__ x, const float* __restrict__ A,
    const float* __restrict__ Bm, const float* __restrict__ lam_p,
    const bf16_t* __restrict__ wp3, const float* __restrict__ biasmat,
    float* __restrict__ out)
{
  __shared__ __align__(16) bf16_t Bs[2 * 128 * 64];  // 32 KB dbuf (also epilogue buf)
  __shared__ __align__(16) bf16_t Xs[256 * 32];      // 16 KB [row=dt*64+ci][v] swizzled
  __shared__ __align__(16) bf16_t Ms[KNUM * 32 * 32];// 12 KB [k][w][v] swizzled, zero-pad

  const int b = blockIdx.x;
  const int half = b >> 9;               // 0..1 : c-range half
  const int rest = b & 511;
  const int n = rest >> 4;               // 0..31
  const int t0 = (rest & 15) << 2;       // t-group of 4
  const int tid = threadIdx.x;
  const int wv = tid >> 6, ln = tid & 63;
  const int lw = ln & 15, lg = ln >> 4;
  const float lam = lam_p[0];

  // stage Ms once: row R=k*32+w (64B), group-XOR sw2=(w&3)^((w>>2)&3)
  for (int i = tid; i < KNUM * 32 * 32; i += 512) {
    int R = i >> 5, v = i & 31;
    int k = i >> 10, w = (i >> 5) & 31;
    float val = 0.f;
    if (w < VV && v < VV)
      val = (k < ET) ? A[(k * VV + v) * VV + w]
                     : lam * Bm[(((n * ET) + (k - ET)) * VV + v) * VV + w];
    int sw2 = (w & 3) ^ ((w >> 2) & 3);
    int byteoff = R * 64 + ((((v >> 3) ^ sw2) & 3) << 4) + ((v & 7) << 1);
    *(bf16_t*)((char*)Ms + byteoff) = (bf16_t)val;
  }

  f32x4 acc[2][4] = {};
  const int miB = half * 8 + (wv >> 1) * 2;  // mi base (16-row tiles) for A-frags
  const int n_base = (wv & 1) * 64;
  const f32x4 z4 = {0.f, 0.f, 0.f, 0.f};
  const int msw2 = (lw & 3) ^ ((lw >> 2) & 3);   // Ms read swizzle

  for (int cb = 0; cb < 4; ++cb) {
    __syncthreads();   // prior readers of Xs/Bs done
    // stage Xs with ALL 512 threads: gh = v-half (waves 0-3: v0..15, 4-7: v16..24)
    {
      int jj = tid & 255, gh = tid >> 8;
      int ci = jj >> 2, dt = jj & 3;
      const float* xp = x + ((long)(n * CIN + cb * 64 + ci) * TDIM + t0 + dt) * VV + gh * 16;
      float xv[16];
      #pragma unroll
      for (int v = 0; v < 16; ++v) xv[v] = 0.f;
      if (gh == 0) {
        #pragma unroll
        for (int v = 0; v < 16; ++v) xv[v] = xp[v];
      } else {
        #pragma unroll
        for (int v = 0; v < 9; ++v) xv[v] = xp[v];
      }
      int row = dt * 64 + ci;
      int sw = (row & 3) ^ ((row >> 2) & 3);
      #pragma unroll
      for (int g2 = 0; g2 < 2; ++g2) {
        int g = gh * 2 + g2;
        char* base = (char*)Xs + row * 64 + ((g ^ sw) & 3) * 16;
        #pragma unroll
        for (int p = 0; p < 4; ++p) {
          int vl = g2 * 8 + p * 2;
          *(unsigned*)(base + p * 4) = packbf(xv[vl], xv[vl + 1]);
        }
      }
    }
    __syncthreads();   // Xs visible

    #pragma unroll 1
    for (int k = 0; k < KNUM; ++k) {
      const int s = cb * 6 + k;
      const int buf = (s & 1) * (128 * 64);
      // A fragments direct global->VGPR (coalesced 16B/lane, L2-hot)
      bf16x8 af2[2][2];
      const bf16_t* wpS = wp3 + (((long)s * 2048 + (long)miB * 128 + ln) << 3);
      #pragma unroll
      for (int kk = 0; kk < 2; ++kk)
        #pragma unroll
        for (int i = 0; i < 2; ++i)
          af2[kk][i] = *(const bf16x8*)(wpS + ((i * 128 + kk * 64) << 3));

      // MFMA#1: Xs x Ms -> Bs[buf] (b64 pack-writes, conflict-floor)
      bf16x8 mb0 = *(const bf16x8*)((const char*)Ms + (k * 32 + lw) * 64 + (((lg ^ msw2) & 3) << 4));
      bf16x8 mb1 = *(const bf16x8*)((const char*)Ms + (k * 32 + 16 + lw) * 64 + (((lg ^ msw2) & 3) << 4));
      #pragma unroll
      for (int rt = 0; rt < 2; ++rt) {
        int arow = wv * 32 + rt * 16 + lw;
        int sw = (arow & 3) ^ ((arow >> 2) & 3);
        int off = ((lg ^ sw) & 3) << 4;
        bf16x8 af = *(const bf16x8*)((const char*)Xs + arow * 64 + off);
        f32x4 d0 = __builtin_amdgcn_mfma_f32_16x16x32_bf16(af, mb0, z4, 0, 0, 0);
        f32x4 d1 = __builtin_amdgcn_mfma_f32_16x16x32_bf16(af, mb1, z4, 0, 0, 0);
        int rbase = wv * 32 + rt * 16 + (lg << 2);
        int dt = rbase >> 6, ci0 = rbase & 63;
        int r0 = dt * 32 + lw;
        int g0 = ((ci0 >> 3) ^ (r0 & 7)) & 7;
        uint2 p0; p0.x = packbf(d0[0], d0[1]); p0.y = packbf(d0[2], d0[3]);
        *(uint2*)((char*)(Bs + buf) + r0 * 128 + (g0 << 4) + ((ci0 << 1) & 15)) = p0;
        uint2 p1; p1.x = packbf(d1[0], d1[1]); p1.y = packbf(d1[2], d1[3]);
        *(uint2*)((char*)(Bs + buf) + (r0 + 16) * 128 + (g0 << 4) + ((ci0 << 1) & 15)) = p1;
      }
      __syncthreads();   // Bs[buf] ready (1 barrier/step; dbuf)

      // MFMA#2: acc += af2 x Bs[buf]
      __builtin_amdgcn_s_setprio(1);
      #pragma unroll
      for (int kk = 0; kk < 2; ++kk) {
        bf16x8 bf2[4];
        #pragma unroll
        for (int j = 0; j < 4; ++j) {
          int rr = n_base + j * 16 + lw;
          int gg = ((kk * 4 + lg) ^ (rr & 7)) & 7;
          bf2[j] = *(const bf16x8*)((const char*)(Bs + buf) + rr * 128 + (gg << 4));
        }
        #pragma unroll
        for (int i = 0; i < 2; ++i)
          #pragma unroll
          for (int j = 0; j < 4; ++j)
            acc[i][j] = __builtin_amdgcn_mfma_f32_16x16x32_bf16(af2[kk][i], bf2[j], acc[i][j], 0, 0, 0);
      }
      __builtin_amdgcn_s_setprio(0);
    }
  }

  // ---- epilogue: LDS bounce -> dense out writes -----------------------------
  // chunks of 32 c; eb[2][32][124] f32 (15,872B x2 = 31,744B, fits in Bs).
  // col_lds = dt*31 + w (w<25). Bias added at readout.
  __syncthreads();   // all #2 reads of Bs done
  float* eb = (float*)Bs;
  const int q = wv >> 1;          // this wave's chunk 0..3
  const int slot = q & 1;
  #pragma unroll 1
  for (int rnd = 0; rnd < 2; ++rnd) {
    if ((q >> 1) == rnd) {
      #pragma unroll
      for (int i = 0; i < 2; ++i)
        #pragma unroll
        for (int j = 0; j < 4; ++j) {
          int col = n_base + j * 16 + lw;
          int dt = col >> 5, w = col & 31;
          if (w < VV) {
            #pragma unroll
            for (int r = 0; r < 4; ++r) {
              int cl = i * 16 + (lg << 2) + r;
              eb[(slot * 32 + cl) * 124 + dt * 31 + w] = acc[i][j][r];
            }
          }
        }
    }
    __syncthreads();
    {
      int ch = tid >> 8, c = (tid >> 3) & 31, dt = (tid >> 1) & 3, wh = tid & 1;
      int qq = rnd * 2 + ch;
      int cg = half * 128 + qq * 32 + c;
      const float* src = eb + (ch * 32 + c) * 124 + dt * 31 + wh * 13;
      float* dst = out + (long)n * 409600 + (long)cg * 1600 + (t0 + dt) * 25 + wh * 13;
      const float* bb = biasmat + n * 25 * 256 + cg;
      int cnt = wh ? 12 : 13;
      for (int it = 0; it < cnt; ++it)
        dst[it] = src[it] + bb[(wh * 13 + it) * 256];
    }
    __syncthreads();
  }
}

// ---------------- ws-free fp32 fallback (insurance) ----------------
__global__ __launch_bounds__(256) void fallback_kernel(
    const float* __restrict__ x, const float* __restrict__ A,
    const float* __restrict__ Bm, const float* __restrict__ lam_p,
    const float* __restrict__ W, const float* __restrict__ bvec,
    float* __restrict__ out)
{
  __shared__ __align__(16) float xs[CIN][28];
  __shared__ __align__(16) float Ms[KNUM][VV][28];   // [k][v][w] padded
  const int nt = blockIdx.x;
  const int n = nt >> 6, t = nt & 63;
  const int tid = threadIdx.x;
  const float lam = lam_p[0];

  const float* xp = x + (((long)(n * CIN + tid) * TDIM + t) * VV);
  #pragma unroll
  for (int v = 0; v < VV; ++v) xs[tid][v] = xp[v];
  xs[tid][25] = xs[tid][26] = xs[tid][27] = 0.f;
  for (int i = tid; i < KNUM * VV * VV; i += 256) {
    int k = i / (VV * VV);
    int r = i - k * VV * VV;
    int v = r / VV;
    int w = r - v * VV;
    Ms[k][v][w] = (k < ET) ? A[(k * VV + v) * VV + w]
                           : lam * Bm[(((n * ET) + (k - ET)) * VV + v) * VV + w];
    if (w == 24) { Ms[k][v][25] = Ms[k][v][26] = Ms[k][v][27] = 0.f; }
  }
  __syncthreads();

  float oacc[28] = {};
  for (int k = 0; k < KNUM; ++k) {
    float yv[28];
    float bv = bvec[(k << 8) + tid];
    #pragma unroll
    for (int v = 0; v < 28; ++v) yv[v] = 0.f;
    for (int ci = 0; ci < CIN; ++ci) {
      float wl = W[ci * KD + (k << 8) + tid];
      const f32x4* x4 = (const f32x4*)&xs[ci][0];
      #pragma unroll
      for (int q = 0; q < 7; ++q) {
        f32x4 xv = x4[q];
        yv[q*4+0] += wl*xv[0]; yv[q*4+1] += wl*xv[1];
        yv[q*4+2] += wl*xv[2]; yv[q*4+3] += wl*xv[3];
      }
    }
    #pragma unroll
    for (int v = 0; v < VV; ++v) {
      float yvv = yv[v] + bv;
      const f32x4* m4 = (const f32x4*)&Ms[k][v][0];
      #pragma unroll
      for (int q = 0; q < 7; ++q) {
        f32x4 mv = m4[q];
        oacc[q*4+0] += yvv*mv[0]; oacc[q*4+1] += yvv*mv[1];
        oacc[q*4+2] += yvv*mv[2]; oacc[q*4+3] += yvv*mv[3];
      }
    }
  }
  float* op = out + (((long)(n * COUT + tid) * TDIM + t) * VV);
  #pragma unroll
  for (int w = 0; w < VV; ++w) op[w] = oacc[w];
}

__global__ void copyA_kernel(const float* __restrict__ A, float* __restrict__ outA) {
  int i = blockIdx.x * 256 + threadIdx.x;
  if (i < ACNT) outA[i] = A[i];
}

extern "C" void kernel_launch(void* const* d_in, const int* in_sizes, int n_in,
                              void* d_out, int out_size, void* d_ws, size_t ws_size,
                              hipStream_t stream) {
  const float* x   = (const float*)d_in[0];
  const float* A   = (const float*)d_in[1];
  const float* Bm  = (const float*)d_in[2];
  const float* lam = (const float*)d_in[3];
  const float* W   = (const float*)d_in[4];
  const float* bv  = (const float*)d_in[5];
  float* out = (float*)d_out;

  if (d_ws != nullptr && ws_size >= WS_NEED) {
    bf16_t* wp3     = (bf16_t*)d_ws;
    float*  biasmat = (float*)((char*)d_ws + BIAS_OFF);
    constexpr int PREP_ITEMS = WP3_CHUNKS + NB * VV * COUT + ACNT;
    prep_kernel<<<(PREP_ITEMS + 255) / 256, 256, 0, stream>>>(A, Bm, lam, W, bv, wp3, biasmat, out + OUT0);
    fused_kernel<<<2 * NB * 16, 512, 0, stream>>>(x, A, Bm, lam, wp3, biasmat, out);
  } else {
    fallback_kernel<<<NB * TDIM, 256, 0, stream>>>(x, A, Bm, lam, W, bv, out);
    copyA_kernel<<<(ACNT + 255) / 256, 256, 0, stream>>>(A, out + OUT0);
  }
}

// Round 10
// 92.351 us; speedup vs baseline: 1.3294x; 1.3294x over previous
//
#include <hip/hip_runtime.h>
#include <hip/hip_bf16.h>
#include <stdint.h>

typedef __bf16 bf16_t;
typedef bf16_t bf16x8 __attribute__((ext_vector_type(8)));
typedef float f32x4 __attribute__((ext_vector_type(4)));

#define DEVI static __device__ __forceinline__

constexpr int NB = 32, CIN = 256, COUT = 256, KNUM = 6, ET = 3, TDIM = 64, VV = 25;
constexpr int KD   = KNUM * CIN;       // 1536 contraction dim (k,ci)
constexpr long OUT0 = (long)NB * COUT * TDIM * VV;  // 13107200 (x_sum elems)
constexpr int ACNT = ET * VV * VV;     // 1875 (A copy)

// wp3: W in fragment-order. 24 steps x 2048 chunks x 16B = 768 KB. (R7 layout)
constexpr int NSTEP = 24;              // 4 cb x 6 k
constexpr int WP3_CHUNKS = NSTEP * 2048;
constexpr size_t WP3_BYTES  = (size_t)WP3_CHUNKS * 16;      // 768 KB
constexpr size_t BIAS_OFF   = WP3_BYTES;
constexpr size_t BIAS_BYTES = (size_t)NB * VV * COUT * 4;   // bias [n][w][c] f32
constexpr size_t WS_NEED    = BIAS_OFF + BIAS_BYTES;

DEVI unsigned packbf(float lo, float hi) {
  unsigned short a = __builtin_bit_cast(unsigned short, (bf16_t)lo);
  unsigned short b = __builtin_bit_cast(unsigned short, (bf16_t)hi);
  return ((unsigned)b << 16) | (unsigned)a;
}

// ---------------- prep: wp3 fragment-layout + bias table + A copy ----------
__global__ __launch_bounds__(256) void prep_kernel(
    const float* __restrict__ A, const float* __restrict__ Bm,
    const float* __restrict__ lam_p, const float* __restrict__ W,
    const float* __restrict__ bvec, bf16_t* __restrict__ wp3,
    float* __restrict__ biasmat, float* __restrict__ outA)
{
  int idx = blockIdx.x * 256 + threadIdx.x;
  constexpr int S1 = WP3_CHUNKS;            // 49152 (one 16B chunk per thread)
  constexpr int S2 = S1 + NB * VV * COUT;   // +204800
  constexpr int S3 = S2 + ACNT;
  if (idx < S1) {
    int s  = idx >> 11;
    int r  = idx & 2047;
    int mi = r >> 7;
    int kk = (r >> 6) & 1;
    int ln = r & 63;
    int lg = ln >> 4, lw = ln & 15;
    int cb = s / 6, k = s - cb * 6;
    int cibase = cb * 64 + (lg + 4 * kk) * 8;
    int col = (k << 8) + mi * 16 + lw;
    bf16_t* dst = wp3 + ((long)idx << 3);
    #pragma unroll
    for (int e = 0; e < 8; ++e)
      dst[e] = (bf16_t)W[(cibase + e) * KD + col];
  } else if (idx < S2) {
    // bias[n][w][c] = sum_k b[k*256+c] * S[n,k,w],  S = col-sum of M (lam folded)
    int j = idx - S1;
    int c = j & 255;
    int nw = j >> 8;
    int w = nw % VV;
    int n = nw / VV;
    float lam = lam_p[0];
    float s = 0.f;
    for (int k = 0; k < KNUM; ++k) {
      float sk = 0.f;
      if (k < ET) {
        for (int v = 0; v < VV; ++v) sk += A[(k * VV + v) * VV + w];
      } else {
        for (int v = 0; v < VV; ++v) sk += Bm[(((n * ET) + (k - ET)) * VV + v) * VV + w];
        sk *= lam;
      }
      s += bvec[(k << 8) + c] * sk;
    }
    biasmat[j] = s;
  } else if (idx < S3) {
    int j = idx - S2;
    outA[j] = A[j];   // second tuple output: A passthrough
  }
}

// ---------------- fused kernel (t-split: BN=64, R7 structure) ----------------
// Grid 1024: block = (n, 2 t's). Per step (cb,k): MFMA#1 Xs x Ms -> Bs[buf]
// (dbuf, XOR swizzle); 1 barrier; MFMA#2 (af2 from wp3 global, acc 4x2).
// t-split halves per-block work with ZERO #1 duplication (cols are per-t).
// Regs ~100 <= 128 -> 4 waves/SIMD, 2 blocks/CU (LDS 36 KB).
__global__ __launch_bounds__(512, 4) void fused_kernel(
    const float* __restrict__ x, const float* __restrict__ A,
    const float* __restrict__ Bm, const float* __restrict__ lam_p,
    const bf16_t* __restrict__ wp3, const float* __restrict__ biasmat,
    float* __restrict__ out)
{
  __shared__ __align__(16) bf16_t Bs[2 * 64 * 64];   // 16 KB dbuf, rows 128B
  __shared__ __align__(16) bf16_t Xs[128 * 32];      // 8 KB [row=dt*64+ci][v] swizzled
  __shared__ __align__(16) bf16_t Ms[KNUM * 32 * 32];// 12 KB [k][w][v] swizzled

  const int b = blockIdx.x;
  const int n = b >> 5;                  // 0..31
  const int t0 = (b & 31) << 1;          // t-pair
  const int tid = threadIdx.x;
  const int wv = tid >> 6, ln = tid & 63;
  const int lw = ln & 15, lg = ln >> 4;
  const float lam = lam_p[0];

  // stage Ms once: row R=k*32+w (64B), group-XOR sw2=(w&3)^((w>>2)&3)
  for (int i = tid; i < KNUM * 32 * 32; i += 512) {
    int R = i >> 5, v = i & 31;
    int k = i >> 10, w = (i >> 5) & 31;
    float val = 0.f;
    if (w < VV && v < VV)
      val = (k < ET) ? A[(k * VV + v) * VV + w]
                     : lam * Bm[(((n * ET) + (k - ET)) * VV + v) * VV + w];
    int sw2 = (w & 3) ^ ((w >> 2) & 3);
    int byteoff = R * 64 + ((((v >> 3) ^ sw2) & 3) << 4) + ((v & 7) << 1);
    *(bf16_t*)((char*)Ms + byteoff) = (bf16_t)val;
  }

  f32x4 acc[4][2] = {};
  const int m_base = (wv >> 1) * 64;
  const int mb4 = (wv >> 1) * 4;         // mi base for A-fragments
  const int n_base = (wv & 1) * 32;      // col base within 64
  const f32x4 z4 = {0.f, 0.f, 0.f, 0.f};
  const int msw2 = (lw & 3) ^ ((lw >> 2) & 3);   // Ms read swizzle

  for (int cb = 0; cb < 4; ++cb) {
    __syncthreads();   // prior readers of Xs done
    // stage Xs: tid<256, row = tid>>1 (0..127), gh = tid&1 (v-half)
    if (tid < 256) {
      int row = tid >> 1, gh = tid & 1;
      int dt = row >> 6, ci = row & 63;
      const float* xp = x + ((long)(n * CIN + cb * 64 + ci) * TDIM + t0 + dt) * VV + gh * 16;
      float xv[16];
      #pragma unroll
      for (int v = 0; v < 16; ++v) xv[v] = 0.f;
      if (gh == 0) {
        #pragma unroll
        for (int v = 0; v < 16; ++v) xv[v] = xp[v];
      } else {
        #pragma unroll
        for (int v = 0; v < 9; ++v) xv[v] = xp[v];
      }
      int sw = (row & 3) ^ ((row >> 2) & 3);
      #pragma unroll
      for (int g2 = 0; g2 < 2; ++g2) {
        int g = gh * 2 + g2;
        char* base = (char*)Xs + row * 64 + ((g ^ sw) & 3) * 16;
        #pragma unroll
        for (int p = 0; p < 4; ++p) {
          int vl = g2 * 8 + p * 2;
          *(unsigned*)(base + p * 4) = packbf(xv[vl], xv[vl + 1]);
        }
      }
    }
    __syncthreads();   // Xs visible

    #pragma unroll 1
    for (int k = 0; k < KNUM; ++k) {
      const int s = cb * 6 + k;
      const int buf = (s & 1) * (64 * 64);
      // A fragments direct global->VGPR (coalesced 16B/lane, L2-hot)
      bf16x8 af2[2][4];
      const bf16_t* wpS = wp3 + (((long)s * 2048 + (long)mb4 * 128 + ln) << 3);
      #pragma unroll
      for (int kk = 0; kk < 2; ++kk)
        #pragma unroll
        for (int i = 0; i < 4; ++i)
          af2[kk][i] = *(const bf16x8*)(wpS + ((i * 128 + kk * 64) << 3));

      // MFMA#1: Xs x Ms -> Bs[buf] (each wave: one 16-row tile x 32 w)
      bf16x8 mb0 = *(const bf16x8*)((const char*)Ms + (k * 32 + lw) * 64 + (((lg ^ msw2) & 3) << 4));
      bf16x8 mb1 = *(const bf16x8*)((const char*)Ms + (k * 32 + 16 + lw) * 64 + (((lg ^ msw2) & 3) << 4));
      {
        int arow = wv * 16 + lw;
        int sw = (arow & 3) ^ ((arow >> 2) & 3);
        int off = ((lg ^ sw) & 3) << 4;
        bf16x8 af = *(const bf16x8*)((const char*)Xs + arow * 64 + off);
        f32x4 d0 = __builtin_amdgcn_mfma_f32_16x16x32_bf16(af, mb0, z4, 0, 0, 0);
        f32x4 d1 = __builtin_amdgcn_mfma_f32_16x16x32_bf16(af, mb1, z4, 0, 0, 0);
        int rbase = wv * 16 + (lg << 2);
        int dt = rbase >> 6, ci0 = rbase & 63;
        int r0 = dt * 32 + lw;
        int g0 = ((ci0 >> 3) ^ (r0 & 7)) & 7;
        char* c0 = (char*)(Bs + buf) + r0 * 128 + (g0 << 4) + ((ci0 << 1) & 15);
        *(unsigned*)(c0)     = packbf(d0[0], d0[1]);
        *(unsigned*)(c0 + 4) = packbf(d0[2], d0[3]);
        char* c1 = (char*)(Bs + buf) + (r0 + 16) * 128 + (g0 << 4) + ((ci0 << 1) & 15);
        *(unsigned*)(c1)     = packbf(d1[0], d1[1]);
        *(unsigned*)(c1 + 4) = packbf(d1[2], d1[3]);
      }
      __syncthreads();   // Bs[buf] ready (1 barrier/step; dbuf)

      // MFMA#2: acc += af2 x Bs[buf]
      __builtin_amdgcn_s_setprio(1);
      #pragma unroll
      for (int kk = 0; kk < 2; ++kk) {
        bf16x8 bf2[2];
        #pragma unroll
        for (int j = 0; j < 2; ++j) {
          int rr = n_base + j * 16 + lw;
          int gg = ((kk * 4 + lg) ^ (rr & 7)) & 7;
          bf2[j] = *(const bf16x8*)((const char*)(Bs + buf) + rr * 128 + (gg << 4));
        }
        #pragma unroll
        for (int i = 0; i < 4; ++i)
          #pragma unroll
          for (int j = 0; j < 2; ++j)
            acc[i][j] = __builtin_amdgcn_mfma_f32_16x16x32_bf16(af2[kk][i], bf2[j], acc[i][j], 0, 0, 0);
      }
      __builtin_amdgcn_s_setprio(0);
    }
  }

  // epilogue: C/D map col=lane&15, row=(lane>>4)*4+reg [m89-verified]
  #pragma unroll
  for (int j = 0; j < 2; ++j) {
    int colb = n_base + j * 16 + lw;         // 0..63
    int dt = colb >> 5, w = colb & 31;
    if (w < VV) {
      float* ob = out + (long)n * 409600 + (t0 + dt) * 25 + w;
      const float* brow = biasmat + (n * 25 + w) * 256;
      #pragma unroll
      for (int i = 0; i < 4; ++i) {
        int mb = m_base + i * 16 + (lg << 2);
        #pragma unroll
        for (int r = 0; r < 4; ++r) {
          int m = mb + r;
          ob[(long)m * 1600] = acc[i][j][r] + brow[m];
        }
      }
    }
  }
}

// ---------------- ws-free fp32 fallback (insurance) ----------------
__global__ __launch_bounds__(256) void fallback_kernel(
    const float* __restrict__ x, const float* __restrict__ A,
    const float* __restrict__ Bm, const float* __restrict__ lam_p,
    const float* __restrict__ W, const float* __restrict__ bvec,
    float* __restrict__ out)
{
  __shared__ __align__(16) float xs[CIN][28];
  __shared__ __align__(16) float Ms[KNUM][VV][28];   // [k][v][w] padded
  const int nt = blockIdx.x;
  const int n = nt >> 6, t = nt & 63;
  const int tid = threadIdx.x;
  const float lam = lam_p[0];

  const float* xp = x + (((long)(n * CIN + tid) * TDIM + t) * VV);
  #pragma unroll
  for (int v = 0; v < VV; ++v) xs[tid][v] = xp[v];
  xs[tid][25] = xs[tid][26] = xs[tid][27] = 0.f;
  for (int i = tid; i < KNUM * VV * VV; i += 256) {
    int k = i / (VV * VV);
    int r = i - k * VV * VV;
    int v = r / VV;
    int w = r - v * VV;
    Ms[k][v][w] = (k < ET) ? A[(k * VV + v) * VV + w]
                           : lam * Bm[(((n * ET) + (k - ET)) * VV + v) * VV + w];
    if (w == 24) { Ms[k][v][25] = Ms[k][v][26] = Ms[k][v][27] = 0.f; }
  }
  __syncthreads();

  float oacc[28] = {};
  for (int k = 0; k < KNUM; ++k) {
    float yv[28];
    float bv = bvec[(k << 8) + tid];
    #pragma unroll
    for (int v = 0; v < 28; ++v) yv[v] = 0.f;
    for (int ci = 0; ci < CIN; ++ci) {
      float wl = W[ci * KD + (k << 8) + tid];
      const f32x4* x4 = (const f32x4*)&xs[ci][0];
      #pragma unroll
      for (int q = 0; q < 7; ++q) {
        f32x4 xv = x4[q];
        yv[q*4+0] += wl*xv[0]; yv[q*4+1] += wl*xv[1];
        yv[q*4+2] += wl*xv[2]; yv[q*4+3] += wl*xv[3];
      }
    }
    #pragma unroll
    for (int v = 0; v < VV; ++v) {
      float yvv = yv[v] + bv;
      const f32x4* m4 = (const f32x4*)&Ms[k][v][0];
      #pragma unroll
      for (int q = 0; q < 7; ++q) {
        f32x4 mv = m4[q];
        oacc[q*4+0] += yvv*mv[0]; oacc[q*4+1] += yvv*mv[1];
        oacc[q*4+2] += yvv*mv[2]; oacc[q*4+3] += yvv*mv[3];
      }
    }
  }
  float* op = out + (((long)(n * COUT + tid) * TDIM + t) * VV);
  #pragma unroll
  for (int w = 0; w < VV; ++w) op[w] = oacc[w];
}

__global__ void copyA_kernel(const float* __restrict__ A, float* __restrict__ outA) {
  int i = blockIdx.x * 256 + threadIdx.x;
  if (i < ACNT) outA[i] = A[i];
}

extern "C" void kernel_launch(void* const* d_in, const int* in_sizes, int n_in,
                              void* d_out, int out_size, void* d_ws, size_t ws_size,
                              hipStream_t stream) {
  const float* x   = (const float*)d_in[0];
  const float* A   = (const float*)d_in[1];
  const float* Bm  = (const float*)d_in[2];
  const float* lam = (const float*)d_in[3];
  const float* W   = (const float*)d_in[4];
  const float* bv  = (const float*)d_in[5];
  float* out = (float*)d_out;

  if (d_ws != nullptr && ws_size >= WS_NEED) {
    bf16_t* wp3     = (bf16_t*)d_ws;
    float*  biasmat = (float*)((char*)d_ws + BIAS_OFF);
    constexpr int PREP_ITEMS = WP3_CHUNKS + NB * VV * COUT + ACNT;
    prep_kernel<<<(PREP_ITEMS + 255) / 256, 256, 0, stream>>>(A, Bm, lam, W, bv, wp3, biasmat, out + OUT0);
    fused_kernel<<<NB * 32, 512, 0, stream>>>(x, A, Bm, lam, wp3, biasmat, out);
  } else {
    fallback_kernel<<<NB * TDIM, 256, 0, stream>>>(x, A, Bm, lam, W, bv, out);
    copyA_kernel<<<(ACNT + 255) / 256, 256, 0, stream>>>(A, out + OUT0);
  }
}

// Round 11
// 89.183 us; speedup vs baseline: 1.3767x; 1.0355x over previous
//
#include <hip/hip_runtime.h>
#include <hip/hip_bf16.h>
#include <stdint.h>

typedef __bf16 bf16_t;
typedef bf16_t bf16x8 __attribute__((ext_vector_type(8)));
typedef float f32x4 __attribute__((ext_vector_type(4)));

#define DEVI static __device__ __forceinline__

constexpr int NB = 32, CIN = 256, COUT = 256, KNUM = 6, ET = 3, TDIM = 64, VV = 25;
constexpr int KD   = KNUM * CIN;       // 1536 contraction dim (k,ci)
constexpr long OUT0 = (long)NB * COUT * TDIM * VV;  // 13107200 (x_sum elems)
constexpr int ACNT = ET * VV * VV;     // 1875 (A copy)

// wp3: W in fragment-order. 24 steps x 2048 chunks x 16B = 768 KB. (R7 layout)
constexpr int NSTEP = 24;              // 4 cb x 6 k
constexpr int WP3_CHUNKS = NSTEP * 2048;
constexpr size_t WP3_BYTES  = (size_t)WP3_CHUNKS * 16;      // 768 KB
constexpr size_t BIAS_OFF   = WP3_BYTES;
constexpr size_t BIAS_BYTES = (size_t)NB * VV * COUT * 4;   // bias [n][w][c] f32
constexpr size_t WS_NEED    = BIAS_OFF + BIAS_BYTES;

DEVI unsigned packbf(float lo, float hi) {
  unsigned short a = __builtin_bit_cast(unsigned short, (bf16_t)lo);
  unsigned short b = __builtin_bit_cast(unsigned short, (bf16_t)hi);
  return ((unsigned)b << 16) | (unsigned)a;
}

// ---------------- prep: wp3 fragment-layout + bias table + A copy ----------
__global__ __launch_bounds__(256) void prep_kernel(
    const float* __restrict__ A, const float* __restrict__ Bm,
    const float* __restrict__ lam_p, const float* __restrict__ W,
    const float* __restrict__ bvec, bf16_t* __restrict__ wp3,
    float* __restrict__ biasmat, float* __restrict__ outA)
{
  int idx = blockIdx.x * 256 + threadIdx.x;
  constexpr int S1 = WP3_CHUNKS;            // 49152 (one 16B chunk per thread)
  constexpr int S2 = S1 + NB * VV * COUT;   // +204800
  constexpr int S3 = S2 + ACNT;
  if (idx < S1) {
    int s  = idx >> 11;
    int r  = idx & 2047;
    int mi = r >> 7;
    int kk = (r >> 6) & 1;
    int ln = r & 63;
    int lg = ln >> 4, lw = ln & 15;
    int cb = s / 6, k = s - cb * 6;
    int cibase = cb * 64 + (lg + 4 * kk) * 8;
    int col = (k << 8) + mi * 16 + lw;
    bf16_t* dst = wp3 + ((long)idx << 3);
    #pragma unroll
    for (int e = 0; e < 8; ++e)
      dst[e] = (bf16_t)W[(cibase + e) * KD + col];
  } else if (idx < S2) {
    // bias[n][w][c] = sum_k b[k*256+c] * S[n,k,w],  S = col-sum of M (lam folded)
    int j = idx - S1;
    int c = j & 255;
    int nw = j >> 8;
    int w = nw % VV;
    int n = nw / VV;
    float lam = lam_p[0];
    float s = 0.f;
    for (int k = 0; k < KNUM; ++k) {
      float sk = 0.f;
      if (k < ET) {
        for (int v = 0; v < VV; ++v) sk += A[(k * VV + v) * VV + w];
      } else {
        for (int v = 0; v < VV; ++v) sk += Bm[(((n * ET) + (k - ET)) * VV + v) * VV + w];
        sk *= lam;
      }
      s += bvec[(k << 8) + c] * sk;
    }
    biasmat[j] = s;
  } else if (idx < S3) {
    int j = idx - S2;
    outA[j] = A[j];   // second tuple output: A passthrough
  }
}

// ---------------- fused kernel (R7 layouts, software-pipelined steps) --------
// Rotated schedule per step k: write pk(k) -> BAR -> [issue af2(k+1) loads]
// -> #2(k) MFMAs || #1(k+1) MFMAs (independent: Xs/Ms only). The af2 L2
// latency and #1's ds_reads hide under #2's MFMA cluster. Same dbuf race
// invariants as R7 (write(k+1) to buf(k-1) is after BAR(k); all reads of
// buf(k-1) precede BAR(k)).
__global__ __launch_bounds__(512, 2) void fused_kernel(
    const float* __restrict__ x, const float* __restrict__ A,
    const float* __restrict__ Bm, const float* __restrict__ lam_p,
    const bf16_t* __restrict__ wp3, const float* __restrict__ biasmat,
    float* __restrict__ out)
{
  __shared__ __align__(16) bf16_t Bs[2 * 128 * 64];  // 32 KB dbuf, rows 128B, XOR-swz
  __shared__ __align__(16) bf16_t Xs[256 * 32];      // 16 KB [row=dt*64+ci][v] swizzled
  __shared__ __align__(16) bf16_t Ms[KNUM * 32 * 32];// 12 KB [k][w][v] swizzled, zero-pad

  const int b = blockIdx.x;
  const int n = b >> 4;                  // 0..31
  const int t0 = (b & 15) << 2;          // t-group of 4
  const int tid = threadIdx.x;
  const int wv = tid >> 6, ln = tid & 63;
  const int lw = ln & 15, lg = ln >> 4;
  const float lam = lam_p[0];

  // stage Ms once: row R=k*32+w (64B), group-XOR sw2=(w&3)^((w>>2)&3)
  for (int i = tid; i < KNUM * 32 * 32; i += 512) {
    int R = i >> 5, v = i & 31;
    int k = i >> 10, w = (i >> 5) & 31;
    float val = 0.f;
    if (w < VV && v < VV)
      val = (k < ET) ? A[(k * VV + v) * VV + w]
                     : lam * Bm[(((n * ET) + (k - ET)) * VV + v) * VV + w];
    int sw2 = (w & 3) ^ ((w >> 2) & 3);
    int byteoff = R * 64 + ((((v >> 3) ^ sw2) & 3) << 4) + ((v & 7) << 1);
    *(bf16_t*)((char*)Ms + byteoff) = (bf16_t)val;
  }

  f32x4 acc[4][4] = {};
  const int m_base = (wv >> 1) * 64;
  const int mb4 = (wv >> 1) * 4;         // mi base for A-fragments
  const int n_base = (wv & 1) * 64;
  const f32x4 z4 = {0.f, 0.f, 0.f, 0.f};
  const int msw2 = (lw & 3) ^ ((lw >> 2) & 3);   // Ms read swizzle

  // ---- helpers (all-static under unrolled loops) ----
  auto compute1 = [&](int k, uint2* pk) {
    // MFMA#1 for step k: 4 MFMAs, results packed bf16 into pk[0..3]
    bf16x8 mb0 = *(const bf16x8*)((const char*)Ms + (k * 32 + lw) * 64 + (((lg ^ msw2) & 3) << 4));
    bf16x8 mb1 = *(const bf16x8*)((const char*)Ms + (k * 32 + 16 + lw) * 64 + (((lg ^ msw2) & 3) << 4));
    #pragma unroll
    for (int rt = 0; rt < 2; ++rt) {
      int arow = wv * 32 + rt * 16 + lw;
      int sw = (arow & 3) ^ ((arow >> 2) & 3);
      int off = ((lg ^ sw) & 3) << 4;
      bf16x8 af = *(const bf16x8*)((const char*)Xs + arow * 64 + off);
      f32x4 d0 = __builtin_amdgcn_mfma_f32_16x16x32_bf16(af, mb0, z4, 0, 0, 0);
      f32x4 d1 = __builtin_amdgcn_mfma_f32_16x16x32_bf16(af, mb1, z4, 0, 0, 0);
      uint2 p0; p0.x = packbf(d0[0], d0[1]); p0.y = packbf(d0[2], d0[3]);
      uint2 p1; p1.x = packbf(d1[0], d1[1]); p1.y = packbf(d1[2], d1[3]);
      pk[rt * 2 + 0] = p0;
      pk[rt * 2 + 1] = p1;
    }
  };
  auto loadaf2 = [&](int s, bf16x8 af[2][4]) {
    const bf16_t* wpS = wp3 + (((long)s * 2048 + (long)mb4 * 128 + ln) << 3);
    #pragma unroll
    for (int kk = 0; kk < 2; ++kk)
      #pragma unroll
      for (int i = 0; i < 4; ++i)
        af[kk][i] = *(const bf16x8*)(wpS + ((i * 128 + kk * 64) << 3));
  };
  auto writepk = [&](int buf, const uint2* pk) {
    #pragma unroll
    for (int rt = 0; rt < 2; ++rt) {
      int rbase = wv * 32 + rt * 16 + (lg << 2);
      int dt = rbase >> 6, ci0 = rbase & 63;
      int r0 = dt * 32 + lw;
      int g0 = ((ci0 >> 3) ^ (r0 & 7)) & 7;
      *(uint2*)((char*)(Bs + buf) + r0 * 128 + (g0 << 4) + ((ci0 << 1) & 15)) = pk[rt * 2 + 0];
      *(uint2*)((char*)(Bs + buf) + (r0 + 16) * 128 + (g0 << 4) + ((ci0 << 1) & 15)) = pk[rt * 2 + 1];
    }
  };
  auto mfma2 = [&](int buf, bf16x8 af[2][4]) {
    #pragma unroll
    for (int kk = 0; kk < 2; ++kk) {
      bf16x8 bf2[4];
      #pragma unroll
      for (int j = 0; j < 4; ++j) {
        int rr = n_base + j * 16 + lw;
        int gg = ((kk * 4 + lg) ^ (rr & 7)) & 7;
        bf2[j] = *(const bf16x8*)((const char*)(Bs + buf) + rr * 128 + (gg << 4));
      }
      #pragma unroll
      for (int i = 0; i < 4; ++i)
        #pragma unroll
        for (int j = 0; j < 4; ++j)
          acc[i][j] = __builtin_amdgcn_mfma_f32_16x16x32_bf16(af[kk][i], bf2[j], acc[i][j], 0, 0, 0);
    }
  };

  #pragma unroll 1
  for (int cb = 0; cb < 4; ++cb) {
    __syncthreads();   // all waves done with prior cb's Xs (#1 reads precede last BAR)
    // stage Xs (R7 verbatim): rows dt*64+ci, group-XOR swizzle
    if (tid < 256) {
      int ci = tid >> 2, dt = tid & 3;
      const float* xp = x + ((long)(n * CIN + cb * 64 + ci) * TDIM + t0 + dt) * VV;
      float xv[25];
      #pragma unroll
      for (int v = 0; v < VV; ++v) xv[v] = xp[v];
      int row = dt * 64 + ci;
      int sw = (row & 3) ^ ((row >> 2) & 3);
      #pragma unroll
      for (int g = 0; g < 4; ++g) {
        char* base = (char*)Xs + row * 64 + ((g ^ sw) & 3) * 16;
        #pragma unroll
        for (int p = 0; p < 4; ++p) {
          int v0 = g * 8 + p * 2;
          float lo = (v0     < VV) ? xv[v0 < VV ? v0 : 0]     : 0.f;
          float hi = (v0 + 1 < VV) ? xv[v0 + 1 < VV ? v0 + 1 : 0] : 0.f;
          *(unsigned*)(base + p * 4) = packbf(lo, hi);
        }
      }
    }
    __syncthreads();   // Xs visible

    // prologue: #1 for k=0 + af2 for s=cb*6
    uint2 pk[4];
    bf16x8 af2[2][4];
    compute1(0, pk);
    loadaf2(cb * 6, af2);

    #pragma unroll
    for (int k = 0; k < KNUM; ++k) {
      const int s = cb * 6 + k;
      const int buf = (s & 1) * (128 * 64);
      writepk(buf, pk);
      __syncthreads();   // Bs[buf] ready for all; prior buf readers done
      // issue next step's af2 loads immediately (hidden under #2 + #1)
      bf16x8 af2n[2][4];
      if (k < KNUM - 1) loadaf2(s + 1, af2n);
      __builtin_amdgcn_s_setprio(1);
      mfma2(buf, af2);       // #2(k): 32 MFMA from Bs[buf]
      if (k < KNUM - 1) compute1(k + 1, pk);   // #1(k+1): independent of #2(k)
      __builtin_amdgcn_s_setprio(0);
      if (k < KNUM - 1) {
        #pragma unroll
        for (int kk = 0; kk < 2; ++kk)
          #pragma unroll
          for (int i = 0; i < 4; ++i)
            af2[kk][i] = af2n[kk][i];
      }
    }
  }

  // epilogue: C/D map col=lane&15, row=(lane>>4)*4+reg [m89-verified]
  #pragma unroll
  for (int j = 0; j < 4; ++j) {
    int colb = n_base + j * 16 + lw;         // 0..127
    int dt = colb >> 5, w = colb & 31;
    if (w < VV) {
      float* ob = out + (long)n * 409600 + (t0 + dt) * 25 + w;
      const float* brow = biasmat + (n * 25 + w) * 256;
      #pragma unroll
      for (int i = 0; i < 4; ++i) {
        int mb = m_base + i * 16 + (lg << 2);
        #pragma unroll
        for (int r = 0; r < 4; ++r) {
          int m = mb + r;
          ob[(long)m * 1600] = acc[i][j][r] + brow[m];
        }
      }
    }
  }
}

// ---------------- ws-free fp32 fallback (insurance) ----------------
__global__ __launch_bounds__(256) void fallback_kernel(
    const float* __restrict__ x, const float* __restrict__ A,
    const float* __restrict__ Bm, const float* __restrict__ lam_p,
    const float* __restrict__ W, const float* __restrict__ bvec,
    float* __restrict__ out)
{
  __shared__ __align__(16) float xs[CIN][28];
  __shared__ __align__(16) float Ms[KNUM][VV][28];   // [k][v][w] padded
  const int nt = blockIdx.x;
  const int n = nt >> 6, t = nt & 63;
  const int tid = threadIdx.x;
  const float lam = lam_p[0];

  const float* xp = x + (((long)(n * CIN + tid) * TDIM + t) * VV);
  #pragma unroll
  for (int v = 0; v < VV; ++v) xs[tid][v] = xp[v];
  xs[tid][25] = xs[tid][26] = xs[tid][27] = 0.f;
  for (int i = tid; i < KNUM * VV * VV; i += 256) {
    int k = i / (VV * VV);
    int r = i - k * VV * VV;
    int v = r / VV;
    int w = r - v * VV;
    Ms[k][v][w] = (k < ET) ? A[(k * VV + v) * VV + w]
                           : lam * Bm[(((n * ET) + (k - ET)) * VV + v) * VV + w];
    if (w == 24) { Ms[k][v][25] = Ms[k][v][26] = Ms[k][v][27] = 0.f; }
  }
  __syncthreads();

  float oacc[28] = {};
  for (int k = 0; k < KNUM; ++k) {
    float yv[28];
    float bv = bvec[(k << 8) + tid];
    #pragma unroll
    for (int v = 0; v < 28; ++v) yv[v] = 0.f;
    for (int ci = 0; ci < CIN; ++ci) {
      float wl = W[ci * KD + (k << 8) + tid];
      const f32x4* x4 = (const f32x4*)&xs[ci][0];
      #pragma unroll
      for (int q = 0; q < 7; ++q) {
        f32x4 xv = x4[q];
        yv[q*4+0] += wl*xv[0]; yv[q*4+1] += wl*xv[1];
        yv[q*4+2] += wl*xv[2]; yv[q*4+3] += wl*xv[3];
      }
    }
    #pragma unroll
    for (int v = 0; v < VV; ++v) {
      float yvv = yv[v] + bv;
      const f32x4* m4 = (const f32x4*)&Ms[k][v][0];
      #pragma unroll
      for (int q = 0; q < 7; ++q) {
        f32x4 mv = m4[q];
        oacc[q*4+0] += yvv*mv[0]; oacc[q*4+1] += yvv*mv[1];
        oacc[q*4+2] += yvv*mv[2]; oacc[q*4+3] += yvv*mv[3];
      }
    }
  }
  float* op = out + (((long)(n * COUT + tid) * TDIM + t) * VV);
  #pragma unroll
  for (int w = 0; w < VV; ++w) op[w] = oacc[w];
}

__global__ void copyA_kernel(const float* __restrict__ A, float* __restrict__ outA) {
  int i = blockIdx.x * 256 + threadIdx.x;
  if (i < ACNT) outA[i] = A[i];
}

extern "C" void kernel_launch(void* const* d_in, const int* in_sizes, int n_in,
                              void* d_out, int out_size, void* d_ws, size_t ws_size,
                              hipStream_t stream) {
  const float* x   = (const float*)d_in[0];
  const float* A   = (const float*)d_in[1];
  const float* Bm  = (const float*)d_in[2];
  const float* lam = (const float*)d_in[3];
  const float* W   = (const float*)d_in[4];
  const float* bv  = (const float*)d_in[5];
  float* out = (float*)d_out;

  if (d_ws != nullptr && ws_size >= WS_NEED) {
    bf16_t* wp3     = (bf16_t*)d_ws;
    float*  biasmat = (float*)((char*)d_ws + BIAS_OFF);
    constexpr int PREP_ITEMS = WP3_CHUNKS + NB * VV * COUT + ACNT;
    prep_kernel<<<(PREP_ITEMS + 255) / 256, 256, 0, stream>>>(A, Bm, lam, W, bv, wp3, biasmat, out + OUT0);
    fused_kernel<<<NB * 16, 512, 0, stream>>>(x, A, Bm, lam, wp3, biasmat, out);
  } else {
    fallback_kernel<<<NB * TDIM, 256, 0, stream>>>(x, A, Bm, lam, W, bv, out);
    copyA_kernel<<<(ACNT + 255) / 256, 256, 0, stream>>>(A, out + OUT0);
  }
}